// Round 1
// baseline (959.319 us; speedup 1.0000x reference)
//
#include <hip/hip_runtime.h>
#include <hip/hip_bf16.h>
#include <math.h>

// Problem constants
#define B_   8
#define C_   64
#define H_   128
#define W_   128
#define NPIX 16384           // H*W
#define NTOT (B_ * NPIX)     // 131072 pixels
#define HEADS 8
#define CH    8              // C/HEADS
#define HID   128            // DIM*2
#define DCONV 16             // DIM/4

// ---------------- K1: LN1 + qkv 1x1 conv (64 -> 192) ----------------
__global__ __launch_bounds__(256) void k1_ln_qkv(
    const float* __restrict__ x, const float* __restrict__ lw,
    const float* __restrict__ lb, const float* __restrict__ wq,
    float* __restrict__ qkv) {
  int pix = blockIdx.x * 256 + threadIdx.x;
  int b = pix >> 14, hw = pix & 16383;
  const float* xb = x + (size_t)b * C_ * NPIX + hw;
  float v[64];
  float mu = 0.f;
#pragma unroll
  for (int c = 0; c < 64; ++c) { v[c] = xb[c * NPIX]; mu += v[c]; }
  mu *= (1.f / 64.f);
  float var = 0.f;
#pragma unroll
  for (int c = 0; c < 64; ++c) { float d = v[c] - mu; var += d * d; }
  float rstd = rsqrtf(var * (1.f / 64.f) + 1e-5f);
#pragma unroll
  for (int c = 0; c < 64; ++c) v[c] = (v[c] - mu) * rstd * lw[c] + lb[c];

  float* out = qkv + (size_t)b * 192 * NPIX + hw;
  for (int co = 0; co < 192; ++co) {
    const float* w = wq + co * 64;
    float a0 = 0.f, a1 = 0.f;
#pragma unroll
    for (int ci = 0; ci < 32; ++ci) {
      a0 = fmaf(v[ci], w[ci], a0);
      a1 = fmaf(v[ci + 32], w[ci + 32], a1);
    }
    out[co * NPIX] = a0 + a1;
  }
}

// ---------------- K2: depthwise 3x3, 192 channels per batch ----------------
__global__ __launch_bounds__(256) void k2_dw3x3(
    const float* __restrict__ in, const float* __restrict__ w9,
    float* __restrict__ out) {
  int idx = blockIdx.x * 256 + threadIdx.x;   // over B_*192*NPIX
  int plane = idx >> 14;                      // b*192 + c
  int hw = idx & 16383, h = hw >> 7, ww = hw & 127;
  int c = plane - (plane / 192) * 192;
  const float* wp = w9 + c * 9;
  const float* ip = in + (size_t)plane * NPIX;
  float acc = 0.f;
#pragma unroll
  for (int ky = 0; ky < 3; ++ky) {
    int hh = h + ky - 1;
    if ((unsigned)hh < 128u) {
#pragma unroll
      for (int kx = 0; kx < 3; ++kx) {
        int wx = ww + kx - 1;
        if ((unsigned)wx < 128u) acc = fmaf(wp[ky * 3 + kx], ip[hh * 128 + wx], acc);
      }
    }
  }
  out[(size_t)plane * NPIX + hw] = acc;
}

// ---------------- K3a: per-(b,head) partial sums of qq, kk, S=q.k^T ----------------
// grid = 64 * 8 chunks; block = 256; each thread handles 8 n's
__global__ __launch_bounds__(256) void k3a_scores(
    const float* __restrict__ qkvd, float* __restrict__ partials) {
  int bh = blockIdx.x >> 3;     // b*8 + head
  int chunk = blockIdx.x & 7;
  int b = bh >> 3, head = bh & 7;
  const float* qp = qkvd + (size_t)b * 192 * NPIX + (head * 8) * NPIX;
  const float* kp = qp + 64 * NPIX;

  float acc[80];
#pragma unroll
  for (int i = 0; i < 80; ++i) acc[i] = 0.f;

  int n0 = chunk * 2048 + threadIdx.x;
#pragma unroll 2
  for (int i = 0; i < 8; ++i) {
    int n = n0 + i * 256;
    float qv[8], kv[8];
#pragma unroll
    for (int c = 0; c < 8; ++c) { qv[c] = qp[c * NPIX + n]; kv[c] = kp[c * NPIX + n]; }
#pragma unroll
    for (int c = 0; c < 8; ++c) {
      acc[c]     = fmaf(qv[c], qv[c], acc[c]);       // qq
      acc[8 + c] = fmaf(kv[c], kv[c], acc[8 + c]);   // kk
#pragma unroll
      for (int d = 0; d < 8; ++d)
        acc[16 + c * 8 + d] = fmaf(qv[c], kv[d], acc[16 + c * 8 + d]);
    }
  }
  // wave reduce
#pragma unroll
  for (int i = 0; i < 80; ++i) {
    float v = acc[i];
#pragma unroll
    for (int off = 32; off > 0; off >>= 1) v += __shfl_down(v, off);
    acc[i] = v;
  }
  __shared__ float red[4][80];
  int wave = threadIdx.x >> 6, lane = threadIdx.x & 63;
  if (lane == 0) {
#pragma unroll
    for (int i = 0; i < 80; ++i) red[wave][i] = acc[i];
  }
  __syncthreads();
  if (threadIdx.x < 80) {
    float s = red[0][threadIdx.x] + red[1][threadIdx.x] + red[2][threadIdx.x] + red[3][threadIdx.x];
    partials[(size_t)blockIdx.x * 80 + threadIdx.x] = s;
  }
}

// ---------------- K3b: finalize attention matrix per (b,head) ----------------
__global__ __launch_bounds__(128) void k3b_attn(
    const float* __restrict__ partials, const float* __restrict__ temp,
    const float* __restrict__ mix, float* __restrict__ attn) {
  int bh = blockIdx.x;
  int head = bh & 7;
  __shared__ float s[80];
  if (threadIdx.x < 80) {
    float v = 0.f;
    for (int c = 0; c < 8; ++c) v += partials[(size_t)(bh * 8 + c) * 80 + threadIdx.x];
    s[threadIdx.x] = v;
  }
  __syncthreads();
  if (threadIdx.x < 64) {
    int c = threadIdx.x >> 3;
    float rq = 1.f / fmaxf(sqrtf(s[c]), 1e-12f);
    float rk = 1.f / fmaxf(sqrtf(s[8 + (threadIdx.x & 7)]), 1e-12f);
    float sc = s[16 + threadIdx.x] * rq * rk;
    float z = sc * temp[head];
    float m = z;
#pragma unroll
    for (int off = 1; off < 8; off <<= 1) m = fmaxf(m, __shfl_xor(m, off));
    float e = expf(z - m);
    float sum = e;
#pragma unroll
    for (int off = 1; off < 8; off <<= 1) sum += __shfl_xor(sum, off);
    float sm = e / sum;
    float r = fmaxf(sc, 0.f); r = r * r;
    float m0 = fmaxf(mix[0], mix[1]);
    float e0 = expf(mix[0] - m0), e1 = expf(mix[1] - m0);
    float w0 = e0 / (e0 + e1), w1 = e1 / (e0 + e1);
    attn[bh * 64 + threadIdx.x] = w0 * sm + w1 * r;
  }
}

// ---------------- K4: attn@v + proj 1x1 + residual + LN2 ----------------
__global__ __launch_bounds__(256) void k4_av_proj_ln(
    const float* __restrict__ qkvd, const float* __restrict__ attn,
    const float* __restrict__ x, const float* __restrict__ pw,
    const float* __restrict__ lw, const float* __restrict__ lb,
    float* __restrict__ x1, float* __restrict__ y2) {
  int pix = blockIdx.x * 256 + threadIdx.x;
  int b = pix >> 14, hw = pix & 16383;
  const float* vbase = qkvd + (size_t)b * 192 * NPIX + 128 * NPIX + hw;
  float o[64];
#pragma unroll
  for (int head = 0; head < 8; ++head) {
    float vv[8];
#pragma unroll
    for (int d = 0; d < 8; ++d) vv[d] = vbase[(head * 8 + d) * NPIX];
    const float* a = attn + (b * 8 + head) * 64;
#pragma unroll
    for (int cc = 0; cc < 8; ++cc) {
      float sacc = 0.f;
#pragma unroll
      for (int d = 0; d < 8; ++d) sacc = fmaf(a[cc * 8 + d], vv[d], sacc);
      o[head * 8 + cc] = sacc;
    }
  }
  const float* xb = x + (size_t)b * C_ * NPIX + hw;
  float* x1b = x1 + (size_t)b * C_ * NPIX + hw;
  float mu = 0.f, s2 = 0.f;
  for (int co = 0; co < 64; ++co) {
    float a0 = xb[co * NPIX], a1 = 0.f;
    const float* w = pw + co * 64;
#pragma unroll
    for (int ci = 0; ci < 32; ++ci) {
      a0 = fmaf(w[ci], o[ci], a0);
      a1 = fmaf(w[ci + 32], o[ci + 32], a1);
    }
    float a = a0 + a1;
    x1b[co * NPIX] = a;
    mu += a;
    s2 = fmaf(a, a, s2);
  }
  mu *= (1.f / 64.f);
  float var = s2 * (1.f / 64.f) - mu * mu;
  float rstd = rsqrtf(fmaxf(var, 0.f) + 1e-5f);
  float* y2b = y2 + (size_t)b * C_ * NPIX + hw;
  for (int co = 0; co < 64; ++co) {
    float a = x1b[co * NPIX];
    y2b[co * NPIX] = (a - mu) * rstd * lw[co] + lb[co];
  }
}

// ---------------- K6: pconv (16ch 3x3 dense) + pin 1x1 (64 -> 256) ----------------
__global__ __launch_bounds__(256) void k6_pconv_pin(
    const float* __restrict__ y2, const float* __restrict__ pcw,
    const float* __restrict__ pinw, float* __restrict__ ag) {
  int pix = blockIdx.x * 256 + threadIdx.x;
  int b = pix >> 14, hw = pix & 16383, h = hw >> 7, w = hw & 127;
  const float* yb = y2 + (size_t)b * C_ * NPIX;
  float yv[64];
#pragma unroll
  for (int i = 0; i < 16; ++i) yv[i] = 0.f;
  for (int ci = 0; ci < 16; ++ci) {
    float nb[9];
#pragma unroll
    for (int ky = 0; ky < 3; ++ky) {
      int hh = h + ky - 1;
#pragma unroll
      for (int kx = 0; kx < 3; ++kx) {
        int wx = w + kx - 1;
        nb[ky * 3 + kx] = ((unsigned)hh < 128u && (unsigned)wx < 128u)
                              ? yb[ci * NPIX + hh * 128 + wx] : 0.f;
      }
    }
#pragma unroll
    for (int co = 0; co < 16; ++co) {
      const float* wp = pcw + (co * 16 + ci) * 9;
#pragma unroll
      for (int k = 0; k < 9; ++k) yv[co] = fmaf(wp[k], nb[k], yv[co]);
    }
  }
#pragma unroll
  for (int ci = 16; ci < 64; ++ci) yv[ci] = yb[ci * NPIX + hw];

  float* agb = ag + (size_t)b * 256 * NPIX + hw;
  for (int co = 0; co < 256; ++co) {
    const float* wp = pinw + co * 64;
    float a0 = 0.f, a1 = 0.f;
#pragma unroll
    for (int ci = 0; ci < 32; ++ci) {
      a0 = fmaf(wp[ci], yv[ci], a0);
      a1 = fmaf(wp[ci + 32], yv[ci + 32], a1);
    }
    agb[co * NPIX] = a0 + a1;
  }
}

// ---------------- K7: dw 3x3 + gelu*gate + pout 1x1 + residual ----------------
__global__ __launch_bounds__(256) void k7_dw_gelu_pout(
    const float* __restrict__ ag, const float* __restrict__ dww,
    const float* __restrict__ poutw, const float* __restrict__ x1,
    float* __restrict__ out) {
  int pix = blockIdx.x * 256 + threadIdx.x;
  int b = pix >> 14, hw = pix & 16383, h = hw >> 7, w = hw & 127;
  const float* ab = ag + (size_t)b * 256 * NPIX;
  float acc[64];
#pragma unroll
  for (int i = 0; i < 64; ++i) acc[i] = 0.f;
  for (int ch = 0; ch < 128; ++ch) {
    const float* ap = ab + ch * NPIX;
    const float* wp = dww + ch * 9;
    float ad = 0.f;
#pragma unroll
    for (int ky = 0; ky < 3; ++ky) {
      int hh = h + ky - 1;
      if ((unsigned)hh < 128u) {
#pragma unroll
        for (int kx = 0; kx < 3; ++kx) {
          int wx = w + kx - 1;
          if ((unsigned)wx < 128u) ad = fmaf(wp[ky * 3 + kx], ap[hh * 128 + wx], ad);
        }
      }
    }
    float gv = ab[(128 + ch) * NPIX + hw];
    float gl = 0.5f * ad * (1.f + erff(ad * 0.70710678118654752f));
    float hv = gl * gv;
#pragma unroll
    for (int co = 0; co < 64; ++co) acc[co] = fmaf(poutw[co * 128 + ch], hv, acc[co]);
  }
  const float* x1b = x1 + (size_t)b * C_ * NPIX + hw;
  float* ob = out + (size_t)b * C_ * NPIX + hw;
#pragma unroll
  for (int co = 0; co < 64; ++co) ob[co * NPIX] = x1b[co * NPIX] + acc[co];
}

// ---------------- launch ----------------
extern "C" void kernel_launch(void* const* d_in, const int* in_sizes, int n_in,
                              void* d_out, int out_size, void* d_ws, size_t ws_size,
                              hipStream_t stream) {
  const float* x       = (const float*)d_in[0];
  const float* ln1_w   = (const float*)d_in[1];
  const float* ln1_b   = (const float*)d_in[2];
  const float* qkv_w   = (const float*)d_in[3];
  const float* qkv_dww = (const float*)d_in[4];
  const float* temp    = (const float*)d_in[5];
  const float* mix     = (const float*)d_in[6];
  const float* proj_w  = (const float*)d_in[7];
  const float* ln2_w   = (const float*)d_in[8];
  const float* ln2_b   = (const float*)d_in[9];
  const float* pconv_w = (const float*)d_in[10];
  const float* pin_w   = (const float*)d_in[11];
  const float* dw_w    = (const float*)d_in[12];
  const float* pout_w  = (const float*)d_in[13];
  float* out = (float*)d_out;

  // Workspace layout (elements). Regions reused after their producers/consumers die:
  //   qkv   [0,            25165824)   dead after K2
  //   qkvd  [25165824,     50331648)   dead after K4
  //   x1    [50331648,     58720256)
  //   y2    [0,            8388608)    reuses dead qkv head (written K4)
  //   ag    [8388608,      41943040)   reuses dead qkv tail + qkvd head (written K6)
  //   partials [58720256,  58761216)
  //   attn     [58761216,  58765312)
  float* ws = (float*)d_ws;
  if (ws_size < (size_t)58765312 * 4) return;
  float* qkv   = ws;
  float* qkvd  = ws + 25165824;
  float* x1    = ws + 50331648;
  float* y2    = ws;
  float* ag    = ws + 8388608;
  float* parts = ws + 58720256;
  float* attnb = ws + 58761216;

  k1_ln_qkv<<<NTOT / 256, 256, 0, stream>>>(x, ln1_w, ln1_b, qkv_w, qkv);
  k2_dw3x3<<<(B_ * 192 * NPIX) / 256, 256, 0, stream>>>(qkv, qkv_dww, qkvd);
  k3a_scores<<<64 * 8, 256, 0, stream>>>(qkvd, parts);
  k3b_attn<<<64, 128, 0, stream>>>(parts, temp, mix, attnb);
  k4_av_proj_ln<<<NTOT / 256, 256, 0, stream>>>(qkvd, attnb, x, proj_w, ln2_w, ln2_b, x1, y2);
  k6_pconv_pin<<<NTOT / 256, 256, 0, stream>>>(y2, pconv_w, pin_w, ag);
  k7_dw_gelu_pout<<<NTOT / 256, 256, 0, stream>>>(ag, dw_w, pout_w, x1, out);
}

// Round 2
// 690.373 us; speedup vs baseline: 1.3896x; 1.3896x over previous
//
#include <hip/hip_runtime.h>
#include <math.h>

#define NPIX 16384
#define B_ 8

// ---------------- K0: fold LN1 into qkv weights ----------------
// wq2[co][ci] = wq[co][ci]*lw[ci];  s1[co] = sum_ci wq2;  s2[co] = sum_ci wq*lb
__global__ __launch_bounds__(192) void k0_fold(
    const float* __restrict__ wq, const float* __restrict__ lw,
    const float* __restrict__ lb, float* __restrict__ wq2,
    float* __restrict__ s1, float* __restrict__ s2) {
  int co = threadIdx.x;  // 0..191
  float a = 0.f, bsum = 0.f;
  for (int ci = 0; ci < 64; ++ci) {
    float w = wq[co * 64 + ci];
    float w2 = w * lw[ci];
    wq2[co * 64 + ci] = w2;
    a += w2;
    bsum += w * lb[ci];
  }
  s1[co] = a;
  s2[co] = bsum;
}

// ---------------- K1: LN1-folded qkv GEMM (64 -> 192) ----------------
// block: 256 thr = 4 waves; tile 64 pixels; wave w -> co chunk [48w, 48w+48)
__global__ __launch_bounds__(256) void k1_qkv(
    const float* __restrict__ x, const float* __restrict__ wq2,
    const float* __restrict__ s1, const float* __restrict__ s2,
    float* __restrict__ qkv) {
  __shared__ float lx[64 * 64];
  int tile = blockIdx.x;            // 2048
  int b = tile >> 8;
  int hw0 = (tile & 255) * 64;
  const float* xb = x + (size_t)b * 64 * NPIX + hw0;
  int t = threadIdx.x;
  {
    int p4 = (t & 15) * 4, ch0 = t >> 4;
#pragma unroll
    for (int r = 0; r < 4; ++r) {
      int ch = ch0 + r * 16;
      *(float4*)&lx[ch * 64 + p4] = *(const float4*)(xb + (size_t)ch * NPIX + p4);
    }
  }
  __syncthreads();
  int lane = t & 63;
  int wv = __builtin_amdgcn_readfirstlane(t >> 6);
  int co0 = wv * 48;
  float acc[48];
#pragma unroll
  for (int i = 0; i < 48; ++i) acc[i] = 0.f;
  float sum = 0.f, sq = 0.f;
  for (int ci = 0; ci < 64; ++ci) {
    float v = lx[ci * 64 + lane];
    sum += v;
    sq = fmaf(v, v, sq);
    const float* wr = wq2 + co0 * 64 + ci;
#pragma unroll
    for (int o = 0; o < 48; ++o) acc[o] = fmaf(v, wr[o * 64], acc[o]);
  }
  float mu = sum * (1.f / 64.f);
  float var = sq * (1.f / 64.f) - mu * mu;
  float rstd = rsqrtf(fmaxf(var, 0.f) + 1e-5f);
  float* outb = qkv + (size_t)b * 192 * NPIX + hw0 + lane;
#pragma unroll
  for (int o = 0; o < 48; ++o) {
    int co = co0 + o;
    outb[(size_t)co * NPIX] = acc[o] * rstd - mu * rstd * s1[co] + s2[co];
  }
}

// ---------------- K2: depthwise 3x3, 192 channels per batch ----------------
__global__ __launch_bounds__(256) void k2_dw3x3(
    const float* __restrict__ in, const float* __restrict__ w9,
    float* __restrict__ out) {
  int idx = blockIdx.x * 256 + threadIdx.x;
  int plane = idx >> 14;
  int hw = idx & 16383, h = hw >> 7, ww = hw & 127;
  int c = plane - (plane / 192) * 192;
  const float* wp = w9 + c * 9;
  const float* ip = in + (size_t)plane * NPIX;
  float acc = 0.f;
#pragma unroll
  for (int ky = 0; ky < 3; ++ky) {
    int hh = h + ky - 1;
    if ((unsigned)hh < 128u) {
#pragma unroll
      for (int kx = 0; kx < 3; ++kx) {
        int wx = ww + kx - 1;
        if ((unsigned)wx < 128u) acc = fmaf(wp[ky * 3 + kx], ip[hh * 128 + wx], acc);
      }
    }
  }
  out[(size_t)plane * NPIX + hw] = acc;
}

// ---------------- K3a: partial sums of qq, kk, S=q.k^T (32 chunks) ----------------
__global__ __launch_bounds__(256) void k3a_scores(
    const float* __restrict__ qkvd, float* __restrict__ partials) {
  int bh = blockIdx.x >> 5;
  int chunk = blockIdx.x & 31;
  int b = bh >> 3, head = bh & 7;
  const float* qp = qkvd + (size_t)b * 192 * NPIX + (size_t)(head * 8) * NPIX;
  const float* kp = qp + (size_t)64 * NPIX;
  float acc[80];
#pragma unroll
  for (int i = 0; i < 80; ++i) acc[i] = 0.f;
  int n0 = chunk * 512 + threadIdx.x;
#pragma unroll
  for (int i = 0; i < 2; ++i) {
    int n = n0 + i * 256;
    float qv[8], kv[8];
#pragma unroll
    for (int c = 0; c < 8; ++c) {
      qv[c] = qp[(size_t)c * NPIX + n];
      kv[c] = kp[(size_t)c * NPIX + n];
    }
#pragma unroll
    for (int c = 0; c < 8; ++c) {
      acc[c] = fmaf(qv[c], qv[c], acc[c]);
      acc[8 + c] = fmaf(kv[c], kv[c], acc[8 + c]);
#pragma unroll
      for (int d = 0; d < 8; ++d)
        acc[16 + c * 8 + d] = fmaf(qv[c], kv[d], acc[16 + c * 8 + d]);
    }
  }
#pragma unroll
  for (int i = 0; i < 80; ++i) {
    float v = acc[i];
#pragma unroll
    for (int off = 32; off > 0; off >>= 1) v += __shfl_down(v, off);
    acc[i] = v;
  }
  __shared__ float red[4][80];
  int wave = threadIdx.x >> 6, lane = threadIdx.x & 63;
  if (lane == 0) {
#pragma unroll
    for (int i = 0; i < 80; ++i) red[wave][i] = acc[i];
  }
  __syncthreads();
  if (threadIdx.x < 80) {
    float s = red[0][threadIdx.x] + red[1][threadIdx.x] + red[2][threadIdx.x] + red[3][threadIdx.x];
    partials[(size_t)blockIdx.x * 80 + threadIdx.x] = s;
  }
}

// ---------------- K3b: finalize attention matrix per (b,head) ----------------
__global__ __launch_bounds__(128) void k3b_attn(
    const float* __restrict__ partials, const float* __restrict__ temp,
    const float* __restrict__ mix, float* __restrict__ attn) {
  int bh = blockIdx.x;
  int head = bh & 7;
  __shared__ float s[80];
  if (threadIdx.x < 80) {
    float v = 0.f;
    for (int c = 0; c < 32; ++c) v += partials[(size_t)(bh * 32 + c) * 80 + threadIdx.x];
    s[threadIdx.x] = v;
  }
  __syncthreads();
  if (threadIdx.x < 64) {
    int c = threadIdx.x >> 3;
    float rq = 1.f / fmaxf(sqrtf(s[c]), 1e-12f);
    float rk = 1.f / fmaxf(sqrtf(s[8 + (threadIdx.x & 7)]), 1e-12f);
    float sc = s[16 + threadIdx.x] * rq * rk;
    float z = sc * temp[head];
    float m = z;
#pragma unroll
    for (int off = 1; off < 8; off <<= 1) m = fmaxf(m, __shfl_xor(m, off));
    float e = expf(z - m);
    float sum = e;
#pragma unroll
    for (int off = 1; off < 8; off <<= 1) sum += __shfl_xor(sum, off);
    float sm = e / sum;
    float r = fmaxf(sc, 0.f);
    r = r * r;
    float m0 = fmaxf(mix[0], mix[1]);
    float e0 = expf(mix[0] - m0), e1 = expf(mix[1] - m0);
    float w0 = e0 / (e0 + e1), w1 = e1 / (e0 + e1);
    attn[bh * 64 + threadIdx.x] = w0 * sm + w1 * r;
  }
}

// ---------------- K3c: fold proj @ blockdiag(attn) -> M_b[64][64] ----------------
__global__ __launch_bounds__(256) void k3c_foldproj(
    const float* __restrict__ pw, const float* __restrict__ attn,
    float* __restrict__ M) {
  int b = blockIdx.x;
  int t = threadIdx.x;
  int co = t & 63;
  int g = t >> 6;
  for (int j = 0; j < 16; ++j) {
    int ci = g * 16 + j;
    int head = ci >> 3, d = ci & 7;
    float a = 0.f;
#pragma unroll
    for (int cc = 0; cc < 8; ++cc)
      a = fmaf(pw[co * 64 + head * 8 + cc], attn[(b * 8 + head) * 64 + cc * 8 + d], a);
    M[(size_t)b * 4096 + co * 64 + ci] = a;
  }
}

// ---------------- K4: (proj∘attn) GEMM on v + residual + LN2 ----------------
__global__ __launch_bounds__(256) void k4_av(
    const float* __restrict__ qkvd, const float* __restrict__ M,
    const float* __restrict__ x, const float* __restrict__ lw,
    const float* __restrict__ lb, float* __restrict__ x1,
    float* __restrict__ y2) {
  __shared__ float lv[64 * 64];
  __shared__ float red[8][64];
  int tile = blockIdx.x, b = tile >> 8, hw0 = (tile & 255) * 64;
  const float* vb = qkvd + (size_t)b * 192 * NPIX + (size_t)128 * NPIX + hw0;
  int t = threadIdx.x;
  {
    int p4 = (t & 15) * 4, ch0 = t >> 4;
#pragma unroll
    for (int r = 0; r < 4; ++r) {
      int ch = ch0 + r * 16;
      *(float4*)&lv[ch * 64 + p4] = *(const float4*)(vb + (size_t)ch * NPIX + p4);
    }
  }
  __syncthreads();
  int lane = t & 63;
  int wv = __builtin_amdgcn_readfirstlane(t >> 6);
  int co0 = wv * 16;
  const float* Mb = M + (size_t)b * 4096 + co0 * 64;
  float acc[16];
#pragma unroll
  for (int i = 0; i < 16; ++i) acc[i] = 0.f;
  for (int ci = 0; ci < 64; ++ci) {
    float v = lv[ci * 64 + lane];
#pragma unroll
    for (int o = 0; o < 16; ++o) acc[o] = fmaf(v, Mb[o * 64 + ci], acc[o]);
  }
  const float* xb = x + (size_t)b * 64 * NPIX + hw0 + lane;
  float* x1b = x1 + (size_t)b * 64 * NPIX + hw0 + lane;
  float sum = 0.f, sq = 0.f;
#pragma unroll
  for (int o = 0; o < 16; ++o) {
    float a = acc[o] + xb[(size_t)(co0 + o) * NPIX];
    acc[o] = a;
    x1b[(size_t)(co0 + o) * NPIX] = a;
    sum += a;
    sq = fmaf(a, a, sq);
  }
  red[wv][lane] = sum;
  red[4 + wv][lane] = sq;
  __syncthreads();
  float s = red[0][lane] + red[1][lane] + red[2][lane] + red[3][lane];
  float q = red[4][lane] + red[5][lane] + red[6][lane] + red[7][lane];
  float mu = s * (1.f / 64.f);
  float var = q * (1.f / 64.f) - mu * mu;
  float rstd = rsqrtf(fmaxf(var, 0.f) + 1e-5f);
  float* y2b = y2 + (size_t)b * 64 * NPIX + hw0 + lane;
#pragma unroll
  for (int o = 0; o < 16; ++o)
    y2b[(size_t)(co0 + o) * NPIX] = (acc[o] - mu) * rstd * lw[co0 + o] + lb[co0 + o];
}

// ---------------- K5: pconv 16->16 3x3 dense, LDS halo tile ----------------
__global__ __launch_bounds__(256) void k5_pconv(
    const float* __restrict__ y2, const float* __restrict__ pcw,
    float* __restrict__ pc) {
  __shared__ float ly[16][18 * 18];
  int tile = blockIdx.x;  // 8b x 8ty x 8tx
  int b = tile >> 6;
  int ty = (tile >> 3) & 7, tx = tile & 7;
  int h0 = ty * 16, w0 = tx * 16;
  const float* yb = y2 + (size_t)b * 64 * NPIX;
  for (int i = threadIdx.x; i < 16 * 324; i += 256) {
    int ch = i / 324, r = i - ch * 324;
    int hy = r / 18, hx = r - hy * 18;
    int gh = h0 + hy - 1, gw = w0 + hx - 1;
    float v = 0.f;
    if ((unsigned)gh < 128u && (unsigned)gw < 128u) v = yb[(size_t)ch * NPIX + gh * 128 + gw];
    ly[ch][r] = v;
  }
  __syncthreads();
  int lp = threadIdx.x;
  int py = lp >> 4, px = lp & 15;
  float acc[16];
#pragma unroll
  for (int i = 0; i < 16; ++i) acc[i] = 0.f;
  for (int ci = 0; ci < 16; ++ci) {
    float nb[9];
#pragma unroll
    for (int ky = 0; ky < 3; ++ky)
#pragma unroll
      for (int kx = 0; kx < 3; ++kx) nb[ky * 3 + kx] = ly[ci][(py + ky) * 18 + px + kx];
#pragma unroll
    for (int co = 0; co < 16; ++co) {
      const float* wp = pcw + (co * 16 + ci) * 9;
#pragma unroll
      for (int k = 0; k < 9; ++k) acc[co] = fmaf(wp[k], nb[k], acc[co]);
    }
  }
  float* pcb = pc + (size_t)b * 16 * NPIX + (h0 + py) * 128 + w0 + px;
#pragma unroll
  for (int co = 0; co < 16; ++co) pcb[(size_t)co * NPIX] = acc[co];
}

// ---------------- K6: pin GEMM (64 -> 256) ----------------
// block 512 = 8 waves; tile 64 pixels; wave w -> co chunk [32w, 32w+32)
__global__ __launch_bounds__(512) void k6_pin(
    const float* __restrict__ pc, const float* __restrict__ y2,
    const float* __restrict__ pinw, float* __restrict__ ag) {
  __shared__ float ly[64 * 64];
  int tile = blockIdx.x, b = tile >> 8, hw0 = (tile & 255) * 64;
  int t = threadIdx.x;
  {
    int p4 = (t & 15) * 4, ch0 = t >> 4;  // ch0 0..31
#pragma unroll
    for (int r = 0; r < 2; ++r) {
      int ch = ch0 + r * 32;
      const float* src = (ch < 16)
                             ? pc + (size_t)b * 16 * NPIX + (size_t)ch * NPIX + hw0 + p4
                             : y2 + (size_t)b * 64 * NPIX + (size_t)ch * NPIX + hw0 + p4;
      *(float4*)&ly[ch * 64 + p4] = *(const float4*)src;
    }
  }
  __syncthreads();
  int lane = t & 63;
  int wv = __builtin_amdgcn_readfirstlane(t >> 6);  // 0..7
  int co0 = wv * 32;
  float acc[32];
#pragma unroll
  for (int i = 0; i < 32; ++i) acc[i] = 0.f;
  for (int ci = 0; ci < 64; ++ci) {
    float v = ly[ci * 64 + lane];
    const float* wr = pinw + (size_t)co0 * 64 + ci;
#pragma unroll
    for (int o = 0; o < 32; ++o) acc[o] = fmaf(v, wr[o * 64], acc[o]);
  }
  float* agb = ag + (size_t)b * 256 * NPIX + hw0 + lane;
#pragma unroll
  for (int o = 0; o < 32; ++o) agb[(size_t)(co0 + o) * NPIX] = acc[o];
}

// ---------------- K7a: dw 3x3 + gelu * gate -> h ----------------
__global__ __launch_bounds__(256) void k7a_dwgelu(
    const float* __restrict__ ag, const float* __restrict__ dww,
    float* __restrict__ hbuf) {
  int idx = blockIdx.x * 256 + threadIdx.x;  // B*128*NPIX
  int plane = idx >> 14;
  int hw = idx & 16383, h = hw >> 7, w = hw & 127;
  int b = plane >> 7, ch = plane & 127;
  const float* ap = ag + (size_t)b * 256 * NPIX + (size_t)ch * NPIX;
  const float* wp = dww + ch * 9;
  float a = 0.f;
#pragma unroll
  for (int ky = 0; ky < 3; ++ky) {
    int hh = h + ky - 1;
    if ((unsigned)hh < 128u) {
#pragma unroll
      for (int kx = 0; kx < 3; ++kx) {
        int wx = w + kx - 1;
        if ((unsigned)wx < 128u) a = fmaf(wp[ky * 3 + kx], ap[hh * 128 + wx], a);
      }
    }
  }
  float g = ag[(size_t)b * 256 * NPIX + (size_t)(128 + ch) * NPIX + hw];
  float gl = 0.5f * a * (1.f + erff(a * 0.70710678118654752f));
  hbuf[(size_t)plane * NPIX + hw] = gl * g;
}

// ---------------- K7b: pout GEMM (128 -> 64) + residual ----------------
__global__ __launch_bounds__(256) void k7b_pout(
    const float* __restrict__ hbuf, const float* __restrict__ poutw,
    const float* __restrict__ x1, float* __restrict__ out) {
  __shared__ float lh[128 * 64];  // 32KB
  int tile = blockIdx.x, b = tile >> 8, hw0 = (tile & 255) * 64;
  int t = threadIdx.x;
  const float* hb = hbuf + (size_t)b * 128 * NPIX + hw0;
  {
    int p4 = (t & 15) * 4, ch0 = t >> 4;
#pragma unroll
    for (int r = 0; r < 8; ++r) {
      int ch = ch0 + r * 16;
      *(float4*)&lh[ch * 64 + p4] = *(const float4*)(hb + (size_t)ch * NPIX + p4);
    }
  }
  __syncthreads();
  int lane = t & 63;
  int wv = __builtin_amdgcn_readfirstlane(t >> 6);
  int co0 = wv * 16;
  float acc[16];
#pragma unroll
  for (int i = 0; i < 16; ++i) acc[i] = 0.f;
  for (int ci = 0; ci < 128; ++ci) {
    float v = lh[ci * 64 + lane];
    const float* wr = poutw + (size_t)co0 * 128 + ci;
#pragma unroll
    for (int o = 0; o < 16; ++o) acc[o] = fmaf(v, wr[o * 128], acc[o]);
  }
  const float* x1b = x1 + (size_t)b * 64 * NPIX + hw0 + lane;
  float* ob = out + (size_t)b * 64 * NPIX + hw0 + lane;
#pragma unroll
  for (int o = 0; o < 16; ++o)
    ob[(size_t)(co0 + o) * NPIX] = acc[o] + x1b[(size_t)(co0 + o) * NPIX];
}

// ---------------- launch ----------------
extern "C" void kernel_launch(void* const* d_in, const int* in_sizes, int n_in,
                              void* d_out, int out_size, void* d_ws, size_t ws_size,
                              hipStream_t stream) {
  const float* x       = (const float*)d_in[0];
  const float* ln1_w   = (const float*)d_in[1];
  const float* ln1_b   = (const float*)d_in[2];
  const float* qkv_w   = (const float*)d_in[3];
  const float* qkv_dww = (const float*)d_in[4];
  const float* temp    = (const float*)d_in[5];
  const float* mix     = (const float*)d_in[6];
  const float* proj_w  = (const float*)d_in[7];
  const float* ln2_w   = (const float*)d_in[8];
  const float* ln2_b   = (const float*)d_in[9];
  const float* pconv_w = (const float*)d_in[10];
  const float* pin_w   = (const float*)d_in[11];
  const float* dw_w    = (const float*)d_in[12];
  const float* pout_w  = (const float*)d_in[13];
  float* out = (float*)d_out;

  // Workspace layout (float offsets). Lifetimes:
  //   qkv   [0, 25165824)         k1 -> k2
  //   qkvd  [25165824, 50331648)  k2 -> k4
  //   x1    [50331648, 58720256)  k4 -> k7b
  //   parts [0, 163840)           k3a -> k3b   (qkv dead)
  //   attn  [163840, 167936)      k3b -> k3c
  //   M     [167936, 200704)      k3c -> k4
  //   y2    [262144, 8650752)     k4 -> k5/k6
  //   pc    [8650752, 10747904)   k5 -> k6
  //   ag    [16777216, 50331648)  k6 -> k7a    (qkv tail + qkvd dead)
  //   h     [0, 16777216)         k7a -> k7b   (parts/attn/M/y2/pc dead)
  //   wq2/s1/s2 @ 50331648        k0 -> k1     (x1 region, dead until k4)
  float* ws = (float*)d_ws;
  if (ws_size < (size_t)58720256 * 4) return;
  float* qkv   = ws;
  float* qkvd  = ws + 25165824;
  float* x1    = ws + 50331648;
  float* parts = ws;
  float* attnb = ws + 163840;
  float* M     = ws + 167936;
  float* y2    = ws + 262144;
  float* pc    = ws + 8650752;
  float* ag    = ws + 16777216;
  float* h     = ws;
  float* wq2   = ws + 50331648;
  float* s1    = ws + 50344320;
  float* s2    = ws + 50344704;

  k0_fold<<<1, 192, 0, stream>>>(qkv_w, ln1_w, ln1_b, wq2, s1, s2);
  k1_qkv<<<2048, 256, 0, stream>>>(x, wq2, s1, s2, qkv);
  k2_dw3x3<<<(B_ * 192 * NPIX) / 256, 256, 0, stream>>>(qkv, qkv_dww, qkvd);
  k3a_scores<<<2048, 256, 0, stream>>>(qkvd, parts);
  k3b_attn<<<64, 128, 0, stream>>>(parts, temp, mix, attnb);
  k3c_foldproj<<<8, 256, 0, stream>>>(proj_w, attnb, M);
  k4_av<<<2048, 256, 0, stream>>>(qkvd, M, x, ln2_w, ln2_b, x1, y2);
  k5_pconv<<<512, 256, 0, stream>>>(y2, pconv_w, pc);
  k6_pin<<<2048, 512, 0, stream>>>(pc, y2, pin_w, ag);
  k7a_dwgelu<<<(B_ * 128 * NPIX) / 256, 256, 0, stream>>>(ag, dw_w, h);
  k7b_pout<<<2048, 256, 0, stream>>>(h, pout_w, x1, out);
}

// Round 3
// 234.667 us; speedup vs baseline: 4.0880x; 2.9419x over previous
//
#include <hip/hip_runtime.h>
#include <math.h>

#define NPIX 16384
#define B_ 8

typedef __attribute__((ext_vector_type(4))) float f32x4;
typedef __attribute__((ext_vector_type(8))) short bf16x8;
typedef __attribute__((ext_vector_type(4))) unsigned int u32x4;

__device__ inline unsigned short f2bf(float f) {            // RNE fp32->bf16
  unsigned int u = __builtin_bit_cast(unsigned int, f);
  return (unsigned short)((u + 0x7fffu + ((u >> 16) & 1u)) >> 16);
}
__device__ inline float bf2f(unsigned short h) {
  unsigned int u = ((unsigned int)h) << 16;
  return __builtin_bit_cast(float, u);
}
__device__ inline unsigned int pack2(unsigned short a, unsigned short b) {
  return (unsigned int)a | ((unsigned int)b << 16);
}
__device__ inline f32x4 mfma16(bf16x8 a, bf16x8 b, f32x4 c) {
  return __builtin_amdgcn_mfma_f32_16x16x32_bf16(a, b, c, 0, 0, 0);
}
__device__ inline void unpack8(u32x4 u, float* f) {
#pragma unroll
  for (int i = 0; i < 4; ++i) {
    unsigned int w = u[i];
    f[2 * i]     = __builtin_bit_cast(float, w << 16);
    f[2 * i + 1] = __builtin_bit_cast(float, w & 0xffff0000u);
  }
}

// ---------- K0a: fold LN1 scale into qkv weights (bf16) ----------
__global__ __launch_bounds__(192) void k0a_fold(
    const float* __restrict__ wq, const float* __restrict__ lw,
    const float* __restrict__ lb, unsigned short* __restrict__ wq2,
    float* __restrict__ s1, float* __restrict__ s2) {
  int co = threadIdx.x;
  float a = 0.f, bsum = 0.f;
  for (int ci = 0; ci < 64; ++ci) {
    float w = wq[co * 64 + ci];
    unsigned short hb = f2bf(w * lw[ci]);
    wq2[co * 64 + ci] = hb;
    a += bf2f(hb);                       // s1 must match bf16 values used in GEMM
    bsum = fmaf(w, lb[ci], bsum);
  }
  s1[co] = a;
  s2[co] = bsum;
}

// ---------- K0b: fold pconv into pin -> W'[256][192] bf16 ----------
// k<144: tap t=k>>4, ci=k&15 : sum_m pin[co][m]*pconv[m][ci][t]
// k>=144: pin[co][k-128]  (identity on channels 16..63)
__global__ __launch_bounds__(192) void k0b_foldpin(
    const float* __restrict__ pin, const float* __restrict__ pcw,
    unsigned short* __restrict__ Wp) {
  int co = blockIdx.x, k = threadIdx.x;
  float v;
  if (k < 144) {
    int tap = k >> 4, ci = k & 15;
    v = 0.f;
#pragma unroll
    for (int m = 0; m < 16; ++m)
      v = fmaf(pin[co * 64 + m], pcw[(m * 16 + ci) * 9 + tap], v);
  } else {
    v = pin[co * 64 + (k - 128)];
  }
  Wp[co * 192 + k] = f2bf(v);
}

// ---------- K0c: fp32 -> bf16 weight convert ----------
__global__ __launch_bounds__(256) void k0c_cvt(
    const float* __restrict__ w, unsigned short* __restrict__ o, int n) {
  int i = blockIdx.x * 256 + threadIdx.x;
  if (i < n) o[i] = f2bf(w[i]);
}

// ---------- K1: LN1-folded qkv MFMA GEMM (64 -> 192), bf16 out ----------
__global__ __launch_bounds__(256) void k1_qkv(
    const float* __restrict__ x, const unsigned short* __restrict__ wq2,
    const float* __restrict__ s1, const float* __restrict__ s2,
    unsigned short* __restrict__ qkv) {
  __shared__ __align__(16) unsigned char lx[64 * 128];   // [pix][64ci] bf16, XOR-swizzled
  __shared__ float sumL[4][64], sqL[4][64], muL[64], rsL[64];
  int t = threadIdx.x, blk = blockIdx.x;
  int b = blk >> 8, hw0 = (blk & 255) * 64;
  const float* xb = x + (size_t)b * 64 * NPIX + hw0;
  int p = t & 63, g8 = t >> 6;
  float psum = 0.f, psq = 0.f;
#pragma unroll
  for (int r = 0; r < 2; ++r) {
    int ci0 = g8 * 8 + r * 32;
    float v[8];
#pragma unroll
    for (int j = 0; j < 8; ++j) {
      v[j] = xb[(size_t)(ci0 + j) * NPIX + p];
      psum += v[j];
      psq = fmaf(v[j], v[j], psq);
    }
    u32x4 pk;
#pragma unroll
    for (int j = 0; j < 4; ++j) pk[j] = pack2(f2bf(v[2 * j]), f2bf(v[2 * j + 1]));
    unsigned int addr = ((unsigned)(p * 128 + ci0 * 2)) ^ ((p & 7) << 4);
    *(u32x4*)&lx[addr] = pk;
  }
  sumL[g8][p] = psum;
  sqL[g8][p] = psq;
  __syncthreads();
  if (t < 64) {
    float s = sumL[0][t] + sumL[1][t] + sumL[2][t] + sumL[3][t];
    float q = sqL[0][t] + sqL[1][t] + sqL[2][t] + sqL[3][t];
    float mu = s * (1.f / 64.f);
    float var = q * (1.f / 64.f) - mu * mu;
    muL[t] = mu;
    rsL[t] = rsqrtf(fmaxf(var, 0.f) + 1e-5f);
  }
  __syncthreads();
  int lane = t & 63, wv = t >> 6, l16 = lane & 15, g = lane >> 4;
  int co0 = wv * 48;
  bf16x8 A[3][2];
#pragma unroll
  for (int ct = 0; ct < 3; ++ct) {
    int co = co0 + ct * 16 + l16;
#pragma unroll
    for (int kh = 0; kh < 2; ++kh)
      A[ct][kh] = *(const bf16x8*)(wq2 + (size_t)co * 64 + kh * 32 + g * 8);
  }
  f32x4 acc[3][4];
#pragma unroll
  for (int ct = 0; ct < 3; ++ct)
#pragma unroll
    for (int nt = 0; nt < 4; ++nt) acc[ct][nt] = (f32x4)0.f;
#pragma unroll
  for (int nt = 0; nt < 4; ++nt) {
    int pp = nt * 16 + l16;
#pragma unroll
    for (int kh = 0; kh < 2; ++kh) {
      unsigned int addr = ((unsigned)(pp * 128 + (kh * 32 + g * 8) * 2)) ^ ((pp & 7) << 4);
      bf16x8 Bf = *(const bf16x8*)&lx[addr];
#pragma unroll
      for (int ct = 0; ct < 3; ++ct) acc[ct][nt] = mfma16(A[ct][kh], Bf, acc[ct][nt]);
    }
  }
  unsigned short* ob = qkv + (size_t)b * 192 * NPIX + hw0;
#pragma unroll
  for (int ct = 0; ct < 3; ++ct)
#pragma unroll
    for (int r = 0; r < 4; ++r) {
      int co = co0 + ct * 16 + g * 4 + r;
      float s1v = s1[co], s2v = s2[co];
#pragma unroll
      for (int nt = 0; nt < 4; ++nt) {
        int pl = nt * 16 + l16;
        float val = (acc[ct][nt][r] - muL[pl] * s1v) * rsL[pl] + s2v;
        ob[(size_t)co * NPIX + pl] = f2bf(val);
      }
    }
}

// ---------- K2: depthwise 3x3 bf16, 192 ch/batch, 8 px/thread ----------
__global__ __launch_bounds__(256) void k2_dw3x3(
    const unsigned short* __restrict__ in, const float* __restrict__ w9,
    unsigned short* __restrict__ out) {
  int gid = blockIdx.x * 256 + threadIdx.x;   // pixel-octet id
  int plane = gid >> 11;                      // b*192 + c
  int o = gid & 2047;
  int h = o >> 4, w0 = (o & 15) * 8;
  int c = plane - (plane / 192) * 192;
  const float* wp = w9 + c * 9;
  float wgt[9];
#pragma unroll
  for (int j = 0; j < 9; ++j) wgt[j] = wp[j];
  const unsigned short* ip = in + (size_t)plane * NPIX;
  float row[3][10];
#pragma unroll
  for (int dy = 0; dy < 3; ++dy) {
#pragma unroll
    for (int i = 0; i < 10; ++i) row[dy][i] = 0.f;
    int hh = h + dy - 1;
    if ((unsigned)hh < 128u) {
      const unsigned short* rp = ip + hh * 128 + w0;
      u32x4 m = *(const u32x4*)rp;
      unpack8(m, &row[dy][1]);
      if (w0 > 0) row[dy][0] = bf2f(rp[-1]);
      if (w0 < 120) row[dy][9] = bf2f(rp[8]);
    }
  }
  u32x4 res;
#pragma unroll
  for (int i = 0; i < 8; i += 2) {
    float a0 = 0.f, a1 = 0.f;
#pragma unroll
    for (int dy = 0; dy < 3; ++dy)
#pragma unroll
      for (int dx = 0; dx < 3; ++dx) {
        a0 = fmaf(wgt[dy * 3 + dx], row[dy][i + dx], a0);
        a1 = fmaf(wgt[dy * 3 + dx], row[dy][i + 1 + dx], a1);
      }
    res[i >> 1] = pack2(f2bf(a0), f2bf(a1));
  }
  *(u32x4*)(out + (size_t)plane * NPIX + h * 128 + w0) = res;
}

// ---------- K3a: partial sums of qq, kk, S (bf16 in, fp32 out) ----------
__global__ __launch_bounds__(256) void k3a_scores(
    const unsigned short* __restrict__ qkvd, float* __restrict__ partials) {
  int bh = blockIdx.x >> 5;
  int chunk = blockIdx.x & 31;
  int b = bh >> 3, head = bh & 7;
  const unsigned short* qp = qkvd + (size_t)b * 192 * NPIX + (size_t)(head * 8) * NPIX;
  const unsigned short* kp = qp + (size_t)64 * NPIX;
  float acc[80];
#pragma unroll
  for (int i = 0; i < 80; ++i) acc[i] = 0.f;
  int n0 = chunk * 512 + threadIdx.x;
#pragma unroll
  for (int i = 0; i < 2; ++i) {
    int n = n0 + i * 256;
    float qv[8], kv[8];
#pragma unroll
    for (int c = 0; c < 8; ++c) {
      qv[c] = bf2f(qp[(size_t)c * NPIX + n]);
      kv[c] = bf2f(kp[(size_t)c * NPIX + n]);
    }
#pragma unroll
    for (int c = 0; c < 8; ++c) {
      acc[c] = fmaf(qv[c], qv[c], acc[c]);
      acc[8 + c] = fmaf(kv[c], kv[c], acc[8 + c]);
#pragma unroll
      for (int d = 0; d < 8; ++d)
        acc[16 + c * 8 + d] = fmaf(qv[c], kv[d], acc[16 + c * 8 + d]);
    }
  }
#pragma unroll
  for (int i = 0; i < 80; ++i) {
    float v = acc[i];
#pragma unroll
    for (int off = 32; off > 0; off >>= 1) v += __shfl_down(v, off);
    acc[i] = v;
  }
  __shared__ float red[4][80];
  int wave = threadIdx.x >> 6, lane = threadIdx.x & 63;
  if (lane == 0) {
#pragma unroll
    for (int i = 0; i < 80; ++i) red[wave][i] = acc[i];
  }
  __syncthreads();
  if (threadIdx.x < 80) {
    float s = red[0][threadIdx.x] + red[1][threadIdx.x] + red[2][threadIdx.x] + red[3][threadIdx.x];
    partials[(size_t)blockIdx.x * 80 + threadIdx.x] = s;
  }
}

// ---------- K3b: finalize attention matrix per (b,head) ----------
__global__ __launch_bounds__(128) void k3b_attn(
    const float* __restrict__ partials, const float* __restrict__ temp,
    const float* __restrict__ mix, float* __restrict__ attn) {
  int bh = blockIdx.x;
  int head = bh & 7;
  __shared__ float s[80];
  if (threadIdx.x < 80) {
    float v = 0.f;
    for (int c = 0; c < 32; ++c) v += partials[(size_t)(bh * 32 + c) * 80 + threadIdx.x];
    s[threadIdx.x] = v;
  }
  __syncthreads();
  if (threadIdx.x < 64) {
    int c = threadIdx.x >> 3;
    float rq = 1.f / fmaxf(sqrtf(s[c]), 1e-12f);
    float rk = 1.f / fmaxf(sqrtf(s[8 + (threadIdx.x & 7)]), 1e-12f);
    float sc = s[16 + threadIdx.x] * rq * rk;
    float z = sc * temp[head];
    float m = z;
#pragma unroll
    for (int off = 1; off < 8; off <<= 1) m = fmaxf(m, __shfl_xor(m, off));
    float e = expf(z - m);
    float sum = e;
#pragma unroll
    for (int off = 1; off < 8; off <<= 1) sum += __shfl_xor(sum, off);
    float sm = e / sum;
    float r = fmaxf(sc, 0.f);
    r = r * r;
    float m0 = fmaxf(mix[0], mix[1]);
    float e0 = expf(mix[0] - m0), e1 = expf(mix[1] - m0);
    float w0 = e0 / (e0 + e1), w1 = e1 / (e0 + e1);
    attn[bh * 64 + threadIdx.x] = w0 * sm + w1 * r;
  }
}

// ---------- K3c: fold proj @ blockdiag(attn) -> M_b[64][64] bf16 ----------
__global__ __launch_bounds__(256) void k3c_foldproj(
    const float* __restrict__ pw, const float* __restrict__ attn,
    unsigned short* __restrict__ M) {
  int b = blockIdx.x, t = threadIdx.x;
  int co = t & 63, g = t >> 6;
  for (int j = 0; j < 16; ++j) {
    int ci = g * 16 + j;
    int head = ci >> 3, d = ci & 7;
    float a = 0.f;
#pragma unroll
    for (int cc = 0; cc < 8; ++cc)
      a = fmaf(pw[co * 64 + head * 8 + cc], attn[(b * 8 + head) * 64 + cc * 8 + d], a);
    M[(size_t)b * 4096 + co * 64 + ci] = f2bf(a);
  }
}

// ---------- K4: MFMA (proj∘attn)@v + residual + LN2 ----------
__global__ __launch_bounds__(256) void k4_av(
    const unsigned short* __restrict__ qkvd, const unsigned short* __restrict__ Mb,
    const float* __restrict__ x, const float* __restrict__ lw,
    const float* __restrict__ lb, float* __restrict__ x1,
    unsigned short* __restrict__ y2) {
  __shared__ __align__(16) unsigned char lv[64 * 128];
  __shared__ float sumL[4][64], sqL[4][64], muL[64], rsL[64];
  int t = threadIdx.x, blk = blockIdx.x;
  int b = blk >> 8, hw0 = (blk & 255) * 64;
  const unsigned short* vb = qkvd + (size_t)b * 192 * NPIX + (size_t)128 * NPIX + hw0;
  int p = t & 63, g8 = t >> 6;
#pragma unroll
  for (int r = 0; r < 2; ++r) {
    int ci0 = g8 * 8 + r * 32;
    unsigned short hh[8];
#pragma unroll
    for (int j = 0; j < 8; ++j) hh[j] = vb[(size_t)(ci0 + j) * NPIX + p];
    u32x4 pk;
#pragma unroll
    for (int j = 0; j < 4; ++j) pk[j] = pack2(hh[2 * j], hh[2 * j + 1]);
    unsigned int addr = ((unsigned)(p * 128 + ci0 * 2)) ^ ((p & 7) << 4);
    *(u32x4*)&lv[addr] = pk;
  }
  __syncthreads();
  int lane = t & 63, wv = t >> 6, l16 = lane & 15, g = lane >> 4;
  bf16x8 A[2];
#pragma unroll
  for (int kh = 0; kh < 2; ++kh)
    A[kh] = *(const bf16x8*)(Mb + (size_t)b * 4096 + (size_t)(wv * 16 + l16) * 64 + kh * 32 + g * 8);
  f32x4 acc[4];
#pragma unroll
  for (int nt = 0; nt < 4; ++nt) acc[nt] = (f32x4)0.f;
#pragma unroll
  for (int nt = 0; nt < 4; ++nt) {
    int pp = nt * 16 + l16;
#pragma unroll
    for (int kh = 0; kh < 2; ++kh) {
      unsigned int addr = ((unsigned)(pp * 128 + (kh * 32 + g * 8) * 2)) ^ ((pp & 7) << 4);
      bf16x8 Bf = *(const bf16x8*)&lv[addr];
      acc[nt] = mfma16(A[kh], Bf, acc[nt]);
    }
  }
  const float* xb = x + (size_t)b * 64 * NPIX + hw0;
  float* x1b = x1 + (size_t)b * 64 * NPIX + hw0;
  float vals[4][4];
#pragma unroll
  for (int nt = 0; nt < 4; ++nt) {
    float ps = 0.f, pq = 0.f;
#pragma unroll
    for (int r = 0; r < 4; ++r) {
      int co = wv * 16 + g * 4 + r;
      size_t idx = (size_t)co * NPIX + nt * 16 + l16;
      float a = acc[nt][r] + xb[idx];
      vals[nt][r] = a;
      x1b[idx] = a;
      ps += a;
      pq = fmaf(a, a, pq);
    }
    ps += __shfl_xor(ps, 16); ps += __shfl_xor(ps, 32);
    pq += __shfl_xor(pq, 16); pq += __shfl_xor(pq, 32);
    if (g == 0) { sumL[wv][nt * 16 + l16] = ps; sqL[wv][nt * 16 + l16] = pq; }
  }
  __syncthreads();
  if (t < 64) {
    float s = sumL[0][t] + sumL[1][t] + sumL[2][t] + sumL[3][t];
    float q = sqL[0][t] + sqL[1][t] + sqL[2][t] + sqL[3][t];
    float mu = s * (1.f / 64.f);
    float var = q * (1.f / 64.f) - mu * mu;
    muL[t] = mu;
    rsL[t] = rsqrtf(fmaxf(var, 0.f) + 1e-5f);
  }
  __syncthreads();
  unsigned short* y2b = y2 + (size_t)b * 64 * NPIX + hw0;
#pragma unroll
  for (int nt = 0; nt < 4; ++nt)
#pragma unroll
    for (int r = 0; r < 4; ++r) {
      int co = wv * 16 + g * 4 + r;
      int pl = nt * 16 + l16;
      float yv = (vals[nt][r] - muL[pl]) * rsL[pl] * lw[co] + lb[co];
      y2b[(size_t)co * NPIX + pl] = f2bf(yv);
    }
}

// ---------- K56: fused pconv+pin implicit-conv MFMA GEMM (K=192 -> 256) ----------
__global__ __launch_bounds__(256) void k56_pin(
    const unsigned short* __restrict__ y2, const unsigned short* __restrict__ Wp,
    unsigned short* __restrict__ ag) {
  __shared__ __align__(16) unsigned char hal[3 * 66 * 48];  // [hr][hc][16ci] stride 48B
  __shared__ __align__(16) unsigned char cen[64 * 112];     // [c][48ci] stride 112B
  int t = threadIdx.x, blk = blockIdx.x;
  int b = blk >> 8, rr = blk & 255;
  int row = rr >> 1, chf = rr & 1;
  int c0 = chf * 64;
  const unsigned short* yb = y2 + (size_t)b * 64 * NPIX;
  for (int i = t; i < 3168; i += 256) {       // halo: ci<16, 3 rows, 66 cols
    int ci = i / 198, rem = i - ci * 198;
    int hr = rem / 66, hc = rem - hr * 66;
    int gh = row - 1 + hr, gw = c0 - 1 + hc;
    unsigned short v = 0;
    if ((unsigned)gh < 128u && (unsigned)gw < 128u) v = yb[(size_t)ci * NPIX + gh * 128 + gw];
    *(unsigned short*)&hal[(hr * 66 + hc) * 48 + ci * 2] = v;
  }
  {
    int cib = t >> 6, c = t & 63;             // center: ci 16..63
#pragma unroll
    for (int r = 0; r < 12; ++r) {
      int cci = cib + r * 4;
      unsigned short v = yb[(size_t)(16 + cci) * NPIX + row * 128 + c0 + c];
      *(unsigned short*)&cen[c * 112 + cci * 2] = v;
    }
  }
  __syncthreads();
  int lane = t & 63, wv = t >> 6, l16 = lane & 15, g = lane >> 4;
  f32x4 acc[4][4];
#pragma unroll
  for (int cc = 0; cc < 4; ++cc)
#pragma unroll
    for (int nt = 0; nt < 4; ++nt) acc[cc][nt] = (f32x4)0.f;
#pragma unroll
  for (int m = 0; m < 6; ++m) {
    int kbase = m * 32 + g * 8;
    bf16x8 Bf[4];
#pragma unroll
    for (int nt = 0; nt < 4; ++nt) {
      int cl = nt * 16 + l16;
      const unsigned char* srcp;
      if (kbase < 144) {
        int tap = kbase >> 4;
        int hr = tap / 3, dx = tap - hr * 3;
        srcp = &hal[(hr * 66 + cl + dx) * 48 + (kbase & 15) * 2];
      } else {
        srcp = &cen[cl * 112 + (kbase - 144) * 2];
      }
      Bf[nt] = *(const bf16x8*)srcp;
    }
#pragma unroll
    for (int cc = 0; cc < 4; ++cc) {
      int co = (wv * 4 + cc) * 16 + l16;
      bf16x8 Af = *(const bf16x8*)(Wp + (size_t)co * 192 + kbase);
#pragma unroll
      for (int nt = 0; nt < 4; ++nt) acc[cc][nt] = mfma16(Af, Bf[nt], acc[cc][nt]);
    }
  }
  unsigned short* ab = ag + (size_t)b * 256 * NPIX + row * 128 + c0;
#pragma unroll
  for (int cc = 0; cc < 4; ++cc)
#pragma unroll
    for (int r = 0; r < 4; ++r) {
      int co = (wv * 4 + cc) * 16 + g * 4 + r;
#pragma unroll
      for (int nt = 0; nt < 4; ++nt)
        ab[(size_t)co * NPIX + nt * 16 + l16] = f2bf(acc[cc][nt][r]);
    }
}

// ---------- K7a: dw 3x3 + exact gelu * gate -> h (bf16) ----------
__global__ __launch_bounds__(256) void k7a_dwgelu(
    const unsigned short* __restrict__ ag, const float* __restrict__ dww,
    unsigned short* __restrict__ hbuf) {
  int gid = blockIdx.x * 256 + threadIdx.x;
  int plane = gid >> 11;                      // b*128 + ch
  int o = gid & 2047;
  int h = o >> 4, w0 = (o & 15) * 8;
  int b = plane >> 7, ch = plane & 127;
  const unsigned short* ap = ag + ((size_t)b * 256 + ch) * NPIX;
  const unsigned short* gp = ag + ((size_t)b * 256 + 128 + ch) * NPIX;
  const float* wp = dww + ch * 9;
  float wgt[9];
#pragma unroll
  for (int j = 0; j < 9; ++j) wgt[j] = wp[j];
  float row[3][10];
#pragma unroll
  for (int dy = 0; dy < 3; ++dy) {
#pragma unroll
    for (int i = 0; i < 10; ++i) row[dy][i] = 0.f;
    int hh = h + dy - 1;
    if ((unsigned)hh < 128u) {
      const unsigned short* rp = ap + hh * 128 + w0;
      u32x4 m = *(const u32x4*)rp;
      unpack8(m, &row[dy][1]);
      if (w0 > 0) row[dy][0] = bf2f(rp[-1]);
      if (w0 < 120) row[dy][9] = bf2f(rp[8]);
    }
  }
  float gt[8];
  unpack8(*(const u32x4*)(gp + h * 128 + w0), gt);
  u32x4 res;
#pragma unroll
  for (int i = 0; i < 8; i += 2) {
    float a0 = 0.f, a1 = 0.f;
#pragma unroll
    for (int dy = 0; dy < 3; ++dy)
#pragma unroll
      for (int dx = 0; dx < 3; ++dx) {
        a0 = fmaf(wgt[dy * 3 + dx], row[dy][i + dx], a0);
        a1 = fmaf(wgt[dy * 3 + dx], row[dy][i + 1 + dx], a1);
      }
    float g0 = 0.5f * a0 * (1.f + erff(a0 * 0.70710678118654752f)) * gt[i];
    float g1 = 0.5f * a1 * (1.f + erff(a1 * 0.70710678118654752f)) * gt[i + 1];
    res[i >> 1] = pack2(f2bf(g0), f2bf(g1));
  }
  *(u32x4*)(hbuf + (size_t)plane * NPIX + h * 128 + w0) = res;
}

// ---------- K7b: MFMA pout GEMM (128 -> 64) + residual -> out fp32 ----------
__global__ __launch_bounds__(256) void k7b_pout(
    const unsigned short* __restrict__ hbuf, const unsigned short* __restrict__ wpo,
    const float* __restrict__ x1, float* __restrict__ out) {
  __shared__ __align__(16) unsigned char lh[64 * 256];   // [pix][128ci] bf16 swizzled
  int t = threadIdx.x, blk = blockIdx.x;
  int b = blk >> 8, hw0 = (blk & 255) * 64;
  const unsigned short* hb = hbuf + (size_t)b * 128 * NPIX + hw0;
  int p = t & 63, g8 = t >> 6;
#pragma unroll
  for (int r = 0; r < 4; ++r) {
    int ci0 = g8 * 8 + r * 32;
    unsigned short hh[8];
#pragma unroll
    for (int j = 0; j < 8; ++j) hh[j] = hb[(size_t)(ci0 + j) * NPIX + p];
    u32x4 pk;
#pragma unroll
    for (int j = 0; j < 4; ++j) pk[j] = pack2(hh[2 * j], hh[2 * j + 1]);
    unsigned int addr = ((unsigned)(p * 256 + ci0 * 2)) ^ ((p & 15) << 4);
    *(u32x4*)&lh[addr] = pk;
  }
  __syncthreads();
  int lane = t & 63, wv = t >> 6, l16 = lane & 15, g = lane >> 4;
  bf16x8 A[4];
#pragma unroll
  for (int kh = 0; kh < 4; ++kh)
    A[kh] = *(const bf16x8*)(wpo + (size_t)(wv * 16 + l16) * 128 + kh * 32 + g * 8);
  f32x4 acc[4];
#pragma unroll
  for (int nt = 0; nt < 4; ++nt) acc[nt] = (f32x4)0.f;
#pragma unroll
  for (int nt = 0; nt < 4; ++nt) {
    int pp = nt * 16 + l16;
#pragma unroll
    for (int kh = 0; kh < 4; ++kh) {
      unsigned int addr = ((unsigned)(pp * 256 + (kh * 32 + g * 8) * 2)) ^ ((pp & 15) << 4);
      bf16x8 Bf = *(const bf16x8*)&lh[addr];
      acc[nt] = mfma16(A[kh], Bf, acc[nt]);
    }
  }
  const float* x1b = x1 + (size_t)b * 64 * NPIX + hw0;
  float* ob = out + (size_t)b * 64 * NPIX + hw0;
#pragma unroll
  for (int nt = 0; nt < 4; ++nt)
#pragma unroll
    for (int r = 0; r < 4; ++r) {
      int co = wv * 16 + g * 4 + r;
      size_t idx = (size_t)co * NPIX + nt * 16 + l16;
      ob[idx] = acc[nt][r] + x1b[idx];
    }
}

// ---------- launch ----------
extern "C" void kernel_launch(void* const* d_in, const int* in_sizes, int n_in,
                              void* d_out, int out_size, void* d_ws, size_t ws_size,
                              hipStream_t stream) {
  const float* x       = (const float*)d_in[0];
  const float* ln1_w   = (const float*)d_in[1];
  const float* ln1_b   = (const float*)d_in[2];
  const float* qkv_w   = (const float*)d_in[3];
  const float* qkv_dww = (const float*)d_in[4];
  const float* temp    = (const float*)d_in[5];
  const float* mix     = (const float*)d_in[6];
  const float* proj_w  = (const float*)d_in[7];
  const float* ln2_w   = (const float*)d_in[8];
  const float* ln2_b   = (const float*)d_in[9];
  const float* pconv_w = (const float*)d_in[10];
  const float* pin_w   = (const float*)d_in[11];
  const float* dw_w    = (const float*)d_in[12];
  const float* pout_w  = (const float*)d_in[13];
  float* out = (float*)d_out;

  // Workspace (byte offsets). Lifetimes:
  //   qkv  [0, 50331648)           k1->k2 (bf16)
  //   qkvd [50331648, 100663296)   k2->k4 (bf16)
  //   x1   [100663296, 134217728)  k4->k7b (fp32)
  //   weights [134217728, 134358528)  k0*->k1/k56/k7b
  //   parts @0 (655360), attn @1048576, M @2097152, y2 @4194304 (16.8MB) -- in dead qkv
  //   ag   [33554432, 100663296)   k56->k7a (dead qkv tail + dead qkvd)
  //   h    [0, 33554432)           k7a->k7b (everything there dead)
  if (ws_size < (size_t)134358528) return;
  char* w8 = (char*)d_ws;
  unsigned short* qkv  = (unsigned short*)(w8 + 0);
  unsigned short* qkvd = (unsigned short*)(w8 + 50331648);
  float*          x1   = (float*)(w8 + 100663296);
  unsigned short* wq2  = (unsigned short*)(w8 + 134217728);
  float*          s1   = (float*)(w8 + 134242304);
  float*          s2   = (float*)(w8 + 134243072);
  unsigned short* Wp   = (unsigned short*)(w8 + 134243840);
  unsigned short* wpo  = (unsigned short*)(w8 + 134342144);
  float*          parts= (float*)(w8 + 0);
  float*          attnb= (float*)(w8 + 1048576);
  unsigned short* M    = (unsigned short*)(w8 + 2097152);
  unsigned short* y2   = (unsigned short*)(w8 + 4194304);
  unsigned short* ag   = (unsigned short*)(w8 + 33554432);
  unsigned short* h    = (unsigned short*)(w8 + 0);

  k0a_fold<<<1, 192, 0, stream>>>(qkv_w, ln1_w, ln1_b, wq2, s1, s2);
  k0b_foldpin<<<256, 192, 0, stream>>>(pin_w, pconv_w, Wp);
  k0c_cvt<<<32, 256, 0, stream>>>(pout_w, wpo, 8192);
  k1_qkv<<<2048, 256, 0, stream>>>(x, wq2, s1, s2, qkv);
  k2_dw3x3<<<12288, 256, 0, stream>>>(qkv, qkv_dww, qkvd);
  k3a_scores<<<2048, 256, 0, stream>>>(qkvd, parts);
  k3b_attn<<<64, 128, 0, stream>>>(parts, temp, mix, attnb);
  k3c_foldproj<<<8, 256, 0, stream>>>(proj_w, attnb, M);
  k4_av<<<2048, 256, 0, stream>>>(qkvd, M, x, ln2_w, ln2_b, x1, y2);
  k56_pin<<<2048, 256, 0, stream>>>(y2, Wp, ag);
  k7a_dwgelu<<<8192, 256, 0, stream>>>(ag, dw_w, h);
  k7b_pout<<<2048, 256, 0, stream>>>(h, wpo, x1, out);
}